// Round 6
// baseline (206.512 us; speedup 1.0000x reference)
//
#include <hip/hip_runtime.h>
#include <math.h>

#define B_SZ 4
#define LSEQ 2048
#define DDIM 768
#define NST  16
#define NROW (B_SZ * LSEQ)      // 8192
#define NJ   33                 // 16 B + 16 C + 1 s1

#define NC   64                 // chunks
#define CS   (LSEQ / NC)        // 32
#define WARM 5                  // warmup chunks; exp(-~25*5) == 0.0f exactly (validated r5)

// ================= projection: thread=(row, k-slice), W via s_load =================
#define KSPL 16
#define KCH  (DDIM / KSPL)      // 48 floats per slice

__global__ __launch_bounds__(256) void proj_part_kernel(
    const float* __restrict__ x,
    const float* __restrict__ Wb, const float* __restrict__ Wc,
    const float* __restrict__ W1, float* __restrict__ part)
{
    const int row = blockIdx.x * 256 + threadIdx.x;
    const int s = blockIdx.y;
    const int k0 = s * KCH;

    float4 xv[KCH / 4];
    const float* xp = x + (size_t)row * DDIM + k0;
    #pragma unroll
    for (int q = 0; q < KCH / 4; ++q) xv[q] = *(const float4*)(xp + q * 4);

    float acc[NJ];
    #pragma unroll
    for (int j = 0; j < NJ; ++j) {
        const float* wrow = (j < 16) ? (Wb + j * DDIM)
                          : (j < 32) ? (Wc + (j - 16) * DDIM)
                                     : W1;
        const float* wk = wrow + k0;   // lane-invariant -> s_load stream
        float a = 0.f;
        #pragma unroll
        for (int q = 0; q < KCH / 4; ++q) {
            a = fmaf(xv[q].x, wk[q * 4 + 0], a);
            a = fmaf(xv[q].y, wk[q * 4 + 1], a);
            a = fmaf(xv[q].z, wk[q * 4 + 2], a);
            a = fmaf(xv[q].w, wk[q * 4 + 3], a);
        }
        acc[j] = a;
    }
    #pragma unroll
    for (int j = 0; j < NJ; ++j)
        part[((size_t)s * NJ + j) * NROW + row] = acc[j];
}

__global__ __launch_bounds__(256) void proj_reduce_kernel(
    const float* __restrict__ part,
    const float* __restrict__ bb, const float* __restrict__ bc,
    const float* __restrict__ b1,
    float* __restrict__ Bp, float* __restrict__ Cc, float* __restrict__ s1)
{
    const int idx = blockIdx.x * 256 + threadIdx.x;
    if (idx >= NJ * NROW) return;
    const int j = idx / NROW;
    const int row = idx % NROW;
    float a = 0.f;
    #pragma unroll
    for (int s = 0; s < KSPL; ++s)
        a += part[((size_t)s * NJ + j) * NROW + row];
    if (j < 16)      Bp[(size_t)row * NST + j] = a + bb[j];
    else if (j < 32) Cc[(size_t)row * NST + (j - 16)] = a + bc[j - 16];
    else             s1[row] = a + b1[0];
}

// ================= scan helpers =================
__device__ __forceinline__ float softplus_f(float z) {
    float t = __expf(-fabsf(z));
    return fmaxf(z, 0.f) + __logf(1.f + t);
}

__device__ __forceinline__ void powers16(float p, float* e) {
    e[0] = p;      e[1] = p * p;      e[2] = e[1] * p;   e[3] = e[1] * e[1];
    e[4] = e[3] * p;  e[5] = e[3] * e[1];  e[6] = e[3] * e[2];  e[7] = e[3] * e[3];
    e[8] = e[7] * p;  e[9] = e[7] * e[1];  e[10] = e[7] * e[2]; e[11] = e[7] * e[3];
    e[12] = e[7] * e[4]; e[13] = e[7] * e[5]; e[14] = e[7] * e[6]; e[15] = e[7] * e[7];
}

__device__ __forceinline__ bool a_structured(const float* acoef) {
    bool st = true;
    #pragma unroll
    for (int n = 0; n < NST; ++n)
        st = st && (fabsf(acoef[n] - (float)(n + 1) * acoef[0]) <= 1e-5f * fabsf(acoef[n]));
    return __all(st) != 0;
}

// ================= fused scan: warmup recompute + output chunk =================
// Block (dblk, c, b): recompute h from zero starting at chunk c-WARM (exact in
// fp32: truncated terms carry factor exp(-S) with S > 100 -> 0.0f, the same
// semantics as round-5's validated P==0 early exit), then emit out for chunk c.
// No Q/Ssum/Hin, no inter-block dependency, 3 launches total.
__global__ __launch_bounds__(256) void scan_kernel(
    const float* __restrict__ x, const float* __restrict__ A_log,
    const float* __restrict__ Wd, const float* __restrict__ bd,
    const float* __restrict__ Bp, const float* __restrict__ Cc,
    const float* __restrict__ s1, float* __restrict__ out)
{
    const int tid = threadIdx.x;
    const int d = blockIdx.x * 256 + tid;
    const int c = blockIdx.y, b = blockIdx.z;

    const float wd = Wd[d], bdv = bd[d];
    float acoef[NST];
    #pragma unroll
    for (int n = 0; n < NST; ++n) acoef[n] = -__expf(A_log[d * NST + n]);
    const float a0 = acoef[0];
    const bool structured = a_structured(acoef);

    float h[NST];
    #pragma unroll
    for (int n = 0; n < NST; ++n) h[n] = 0.f;

    const int j0 = (c >= WARM) ? (c - WARM) : 0;

    // ---- warmup: h-recurrence only, chunks [j0, c) ----
    for (int j = j0; j < c; ++j) {
        const int rowbase = b * LSEQ + j * CS;
        const float* s1p = s1 + rowbase;
        const float* xp = x + (size_t)rowbase * DDIM + d;
        const float4* B4 = (const float4*)(Bp + (size_t)rowbase * NST);
        if (structured) {
            #pragma unroll 4
            for (int l = 0; l < CS; ++l) {
                const float delta = softplus_f(fmaf(s1p[l], wd, bdv));
                float e[NST];
                powers16(__expf(delta * a0), e);
                const float dx = delta * xp[(size_t)l * DDIM];
                const float4 b0 = B4[l * 4 + 0], b1v = B4[l * 4 + 1];
                const float4 b2 = B4[l * 4 + 2], b3v = B4[l * 4 + 3];
                const float bv[NST] = {b0.x, b0.y, b0.z, b0.w, b1v.x, b1v.y, b1v.z, b1v.w,
                                       b2.x, b2.y, b2.z, b2.w, b3v.x, b3v.y, b3v.z, b3v.w};
                #pragma unroll
                for (int n = 0; n < NST; ++n) h[n] = fmaf(e[n], h[n], dx * bv[n]);
            }
        } else {
            #pragma unroll 2
            for (int l = 0; l < CS; ++l) {
                const float delta = softplus_f(fmaf(s1p[l], wd, bdv));
                float e[NST];
                #pragma unroll
                for (int n = 0; n < NST; ++n) e[n] = __expf(delta * acoef[n]);
                const float dx = delta * xp[(size_t)l * DDIM];
                const float4 b0 = B4[l * 4 + 0], b1v = B4[l * 4 + 1];
                const float4 b2 = B4[l * 4 + 2], b3v = B4[l * 4 + 3];
                const float bv[NST] = {b0.x, b0.y, b0.z, b0.w, b1v.x, b1v.y, b1v.z, b1v.w,
                                       b2.x, b2.y, b2.z, b2.w, b3v.x, b3v.y, b3v.z, b3v.w};
                #pragma unroll
                for (int n = 0; n < NST; ++n) h[n] = fmaf(e[n], h[n], dx * bv[n]);
            }
        }
    }

    // ---- output chunk c ----
    {
        const int rowbase = b * LSEQ + c * CS;
        const float* s1p = s1 + rowbase;
        const float* xp = x + (size_t)rowbase * DDIM + d;
        const float4* B4 = (const float4*)(Bp + (size_t)rowbase * NST);
        const float4* C4 = (const float4*)(Cc + (size_t)rowbase * NST);
        float* yp = out + (size_t)rowbase * DDIM + d;

        if (structured) {
            #pragma unroll 4
            for (int l = 0; l < CS; ++l) {
                const float delta = softplus_f(fmaf(s1p[l], wd, bdv));
                float e[NST];
                powers16(__expf(delta * a0), e);
                const float dx = delta * xp[(size_t)l * DDIM];
                const float4 b0 = B4[l * 4 + 0], b1v = B4[l * 4 + 1];
                const float4 b2 = B4[l * 4 + 2], b3v = B4[l * 4 + 3];
                const float4 c0v = C4[l * 4 + 0], c1v = C4[l * 4 + 1];
                const float4 c2v = C4[l * 4 + 2], c3v = C4[l * 4 + 3];
                const float bv[NST] = {b0.x, b0.y, b0.z, b0.w, b1v.x, b1v.y, b1v.z, b1v.w,
                                       b2.x, b2.y, b2.z, b2.w, b3v.x, b3v.y, b3v.z, b3v.w};
                const float cv[NST] = {c0v.x, c0v.y, c0v.z, c0v.w, c1v.x, c1v.y, c1v.z, c1v.w,
                                       c2v.x, c2v.y, c2v.z, c2v.w, c3v.x, c3v.y, c3v.z, c3v.w};
                float y = 0.f;
                #pragma unroll
                for (int n = 0; n < NST; ++n) {
                    h[n] = fmaf(e[n], h[n], dx * bv[n]);
                    y = fmaf(h[n], cv[n], y);
                }
                yp[(size_t)l * DDIM] = y;
            }
        } else {
            #pragma unroll 2
            for (int l = 0; l < CS; ++l) {
                const float delta = softplus_f(fmaf(s1p[l], wd, bdv));
                float e[NST];
                #pragma unroll
                for (int n = 0; n < NST; ++n) e[n] = __expf(delta * acoef[n]);
                const float dx = delta * xp[(size_t)l * DDIM];
                const float4 b0 = B4[l * 4 + 0], b1v = B4[l * 4 + 1];
                const float4 b2 = B4[l * 4 + 2], b3v = B4[l * 4 + 3];
                const float4 c0v = C4[l * 4 + 0], c1v = C4[l * 4 + 1];
                const float4 c2v = C4[l * 4 + 2], c3v = C4[l * 4 + 3];
                const float bv[NST] = {b0.x, b0.y, b0.z, b0.w, b1v.x, b1v.y, b1v.z, b1v.w,
                                       b2.x, b2.y, b2.z, b2.w, b3v.x, b3v.y, b3v.z, b3v.w};
                const float cv[NST] = {c0v.x, c0v.y, c0v.z, c0v.w, c1v.x, c1v.y, c1v.z, c1v.w,
                                       c2v.x, c2v.y, c2v.z, c2v.w, c3v.x, c3v.y, c3v.z, c3v.w};
                float y = 0.f;
                #pragma unroll
                for (int n = 0; n < NST; ++n) {
                    h[n] = fmaf(e[n], h[n], dx * bv[n]);
                    y = fmaf(h[n], cv[n], y);
                }
                yp[(size_t)l * DDIM] = y;
            }
        }
    }
}

extern "C" void kernel_launch(void* const* d_in, const int* in_sizes, int n_in,
                              void* d_out, int out_size, void* d_ws, size_t ws_size,
                              hipStream_t stream) {
    const float* x     = (const float*)d_in[0];
    const float* A_log = (const float*)d_in[1];
    const float* Wb    = (const float*)d_in[2];
    const float* bb    = (const float*)d_in[3];
    const float* Wc    = (const float*)d_in[4];
    const float* bc    = (const float*)d_in[5];
    const float* W1    = (const float*)d_in[6];
    const float* b1    = (const float*)d_in[7];
    const float* Wd    = (const float*)d_in[8];
    const float* bd    = (const float*)d_in[9];
    float* out = (float*)d_out;

    float* ws = (float*)d_ws;
    const size_t partN = (size_t)KSPL * NJ * NROW;     // 4.33M floats
    const size_t BpN = (size_t)NROW * NST;
    const size_t s1N = (size_t)NROW;

    float* part = ws;
    float* Bp   = part + partN;
    float* Cc   = Bp + BpN;
    float* s1   = Cc + BpN;

    dim3 gproj(NROW / 256, KSPL);
    proj_part_kernel<<<gproj, 256, 0, stream>>>(x, Wb, Wc, W1, part);
    proj_reduce_kernel<<<(NJ * NROW + 255) / 256, 256, 0, stream>>>(part, bb, bc, b1, Bp, Cc, s1);

    dim3 gscan(DDIM / 256, NC, B_SZ);
    scan_kernel<<<gscan, 256, 0, stream>>>(x, A_log, Wd, bd, Bp, Cc, s1, out);
}

// Round 7
// 161.090 us; speedup vs baseline: 1.2820x; 1.2820x over previous
//
#include <hip/hip_runtime.h>
#include <math.h>

#define B_SZ 4
#define LSEQ 2048
#define DDIM 768
#define NST  16
#define NROW (B_SZ * LSEQ)      // 8192
#define NJ   33                 // 16 B + 16 C + 1 s1

#define NC   64                 // chunks
#define CS   (LSEQ / NC)        // 32
#define CPG  (NC / 4)           // 16 chunks per shuffle group

// ================= projection: thread=(row, k-slice), W via s_load =================
#define KSPL 16
#define KCH  (DDIM / KSPL)      // 48 floats per slice
#define LP   52                 // LDS row pitch: 208B = 16B-aligned; banks conflict-free

// x staged via LDS with coalesced loads (lane=row would scatter 64x16B at 3KB stride;
// staging reads 192B runs instead). Compute loop unchanged: W is lane-invariant s_load.
__global__ __launch_bounds__(256) void proj_part_kernel(
    const float* __restrict__ x,
    const float* __restrict__ Wb, const float* __restrict__ Wc,
    const float* __restrict__ W1, float* __restrict__ part)
{
    __shared__ float xs[256][LP];       // 52 KB -> 3 blocks/CU by LDS
    const int tid = threadIdx.x;
    const int row0 = blockIdx.x * 256;
    const int s = blockIdx.y;

    // ---- coalesced staging: 3072 float4 = 256 rows x 12 f4; thread does 12 ----
    const float4* x4 = (const float4*)x;
    #pragma unroll
    for (int i = 0; i < 12; ++i) {
        const int idx = i * 256 + tid;          // 0..3071
        const int r = idx / 12, kq = idx % 12;  // row, f4-within-slice
        const float4 v = x4[(size_t)(row0 + r) * (DDIM / 4) + s * 12 + kq];
        float* p = &xs[r][kq * 4];
        p[0] = v.x; p[1] = v.y; p[2] = v.z; p[3] = v.w;
    }
    __syncthreads();

    // own row -> registers (ds_read_b128, 16B-aligned via LP=52)
    float4 xv[KCH / 4];
    #pragma unroll
    for (int q = 0; q < KCH / 4; ++q) xv[q] = *(const float4*)&xs[tid][q * 4];

    const int row = row0 + tid;
    const int k0 = s * KCH;
    float acc[NJ];
    #pragma unroll
    for (int j = 0; j < NJ; ++j) {
        const float* wrow = (j < 16) ? (Wb + j * DDIM)
                          : (j < 32) ? (Wc + (j - 16) * DDIM)
                                     : W1;
        const float* wk = wrow + k0;   // lane-invariant -> s_load stream
        float a = 0.f;
        #pragma unroll
        for (int q = 0; q < KCH / 4; ++q) {
            a = fmaf(xv[q].x, wk[q * 4 + 0], a);
            a = fmaf(xv[q].y, wk[q * 4 + 1], a);
            a = fmaf(xv[q].z, wk[q * 4 + 2], a);
            a = fmaf(xv[q].w, wk[q * 4 + 3], a);
        }
        acc[j] = a;
    }
    #pragma unroll
    for (int j = 0; j < NJ; ++j)
        part[((size_t)s * NJ + j) * NROW + row] = acc[j];
}

__global__ __launch_bounds__(256) void proj_reduce_kernel(
    const float* __restrict__ part,
    const float* __restrict__ bb, const float* __restrict__ bc,
    const float* __restrict__ b1,
    float* __restrict__ Bp, float* __restrict__ Cc, float* __restrict__ s1)
{
    const int idx = blockIdx.x * 256 + threadIdx.x;
    if (idx >= NJ * NROW) return;
    const int j = idx / NROW;
    const int row = idx % NROW;
    float a = 0.f;
    #pragma unroll
    for (int s = 0; s < KSPL; ++s)
        a += part[((size_t)s * NJ + j) * NROW + row];
    if (j < 16)      Bp[(size_t)row * NST + j] = a + bb[j];
    else if (j < 32) Cc[(size_t)row * NST + (j - 16)] = a + bc[j - 16];
    else             s1[row] = a + b1[0];
}

// ================= scan helpers =================
__device__ __forceinline__ float softplus_f(float z) {
    float t = __expf(-fabsf(z));
    return fmaxf(z, 0.f) + __logf(1.f + t);
}

__device__ __forceinline__ void powers16(float p, float* e) {
    e[0] = p;      e[1] = p * p;      e[2] = e[1] * p;   e[3] = e[1] * e[1];
    e[4] = e[3] * p;  e[5] = e[3] * e[1];  e[6] = e[3] * e[2];  e[7] = e[3] * e[3];
    e[8] = e[7] * p;  e[9] = e[7] * e[1];  e[10] = e[7] * e[2]; e[11] = e[7] * e[3];
    e[12] = e[7] * e[4]; e[13] = e[7] * e[5]; e[14] = e[7] * e[6]; e[15] = e[7] * e[7];
}

__device__ __forceinline__ bool a_structured(const float* acoef) {
    bool st = true;
    #pragma unroll
    for (int n = 0; n < NST; ++n)
        st = st && (fabsf(acoef[n] - (float)(n + 1) * acoef[0]) <= 1e-5f * fabsf(acoef[n]));
    return __all(st) != 0;
}

// ================= pass1: LDS-staged chunk scan =================
__global__ __launch_bounds__(256) void pass1_kernel(
    const float* __restrict__ x, const float* __restrict__ A_log,
    const float* __restrict__ Wd, const float* __restrict__ bd,
    const float* __restrict__ Bp, const float* __restrict__ s1,
    float* __restrict__ Ssum, float* __restrict__ Q)
{
    __shared__ float xs[CS][256];   // 32 KB
    __shared__ float bs[CS][NST];   // 2 KB
    __shared__ float ss[CS];

    const int tid = threadIdx.x;
    const int d0 = blockIdx.x * 256;
    const int d = d0 + tid;
    const int c = blockIdx.y, b = blockIdx.z;
    const int rowbase = b * LSEQ + c * CS;

    // ---- bulk staging ----
    {
        const float4* xg = (const float4*)(x + (size_t)rowbase * DDIM + d0);
        #pragma unroll
        for (int i = 0; i < (CS * 256 / 4) / 256; ++i) {       // 8 iters
            const int flat = i * 256 + tid;
            const int r = flat >> 6, q = flat & 63;
            const float4 v = xg[(size_t)r * (DDIM / 4) + q];
            float* p = &xs[r][q * 4];
            p[0] = v.x; p[1] = v.y; p[2] = v.z; p[3] = v.w;
        }
        if (tid < CS * NST / 4) {                              // 128 threads
            const float4 v = ((const float4*)(Bp + (size_t)rowbase * NST))[tid];
            const int r = tid >> 2, q = tid & 3;
            float* p = &bs[r][q * 4];
            p[0] = v.x; p[1] = v.y; p[2] = v.z; p[3] = v.w;
        }
        if (tid < CS) ss[tid] = s1[rowbase + tid];
    }

    const float wd = Wd[d], bdv = bd[d];
    float acoef[NST];
    #pragma unroll
    for (int n = 0; n < NST; ++n) acoef[n] = -__expf(A_log[d * NST + n]);
    const float a0 = acoef[0];
    const bool structured = a_structured(acoef);

    __syncthreads();

    float h[NST];
    #pragma unroll
    for (int n = 0; n < NST; ++n) h[n] = 0.f;
    float S = 0.f;

    if (structured) {
        #pragma unroll 4
        for (int l = 0; l < CS; ++l) {
            const float delta = softplus_f(fmaf(ss[l], wd, bdv));
            S += delta;
            float e[NST];
            powers16(__expf(delta * a0), e);
            const float dx = delta * xs[l][tid];
            const float4 b0 = *(const float4*)&bs[l][0];
            const float4 b1v = *(const float4*)&bs[l][4];
            const float4 b2 = *(const float4*)&bs[l][8];
            const float4 b3v = *(const float4*)&bs[l][12];
            const float bv[NST] = {b0.x, b0.y, b0.z, b0.w, b1v.x, b1v.y, b1v.z, b1v.w,
                                   b2.x, b2.y, b2.z, b2.w, b3v.x, b3v.y, b3v.z, b3v.w};
            #pragma unroll
            for (int n = 0; n < NST; ++n) h[n] = fmaf(e[n], h[n], dx * bv[n]);
        }
    } else {
        #pragma unroll 4
        for (int l = 0; l < CS; ++l) {
            const float delta = softplus_f(fmaf(ss[l], wd, bdv));
            S += delta;
            float e[NST];
            #pragma unroll
            for (int n = 0; n < NST; ++n) e[n] = __expf(delta * acoef[n]);
            const float dx = delta * xs[l][tid];
            const float4 b0 = *(const float4*)&bs[l][0];
            const float4 b1v = *(const float4*)&bs[l][4];
            const float4 b2 = *(const float4*)&bs[l][8];
            const float4 b3v = *(const float4*)&bs[l][12];
            const float bv[NST] = {b0.x, b0.y, b0.z, b0.w, b1v.x, b1v.y, b1v.z, b1v.w,
                                   b2.x, b2.y, b2.z, b2.w, b3v.x, b3v.y, b3v.z, b3v.w};
            #pragma unroll
            for (int n = 0; n < NST; ++n) h[n] = fmaf(e[n], h[n], dx * bv[n]);
        }
    }
    Ssum[((size_t)b * NC + c) * DDIM + d] = S;
    const size_t gbase = (((size_t)b * NC + c) * DDIM + d) * NST;
    float4* Q4 = (float4*)(Q + gbase);
    #pragma unroll
    for (int q = 0; q < 4; ++q)
        Q4[q] = make_float4(h[q * 4], h[q * 4 + 1], h[q * 4 + 2], h[q * 4 + 3]);
}

// ================= combine (validated) =================
__global__ __launch_bounds__(256) void combine_kernel(
    const float* __restrict__ A_log,
    const float* __restrict__ Ssum, const float* __restrict__ Q,
    float* __restrict__ Hin)
{
    const int gidx = blockIdx.x * 256 + threadIdx.x;
    const int lane = threadIdx.x & 63;
    const int rlow = gidx & 15;
    const int g = (gidx >> 4) & 3;
    const int hi = gidx >> 6;
    const int pairIdx = hi * 16 + rlow;            // [0, B*D*N)
    const int b2 = pairIdx / (DDIM * NST);
    const int r = pairIdx % (DDIM * NST);
    const int d2 = r >> 4;
    const float ac = -__expf(A_log[r]);
    const int c0 = g * CPG;

    float eq[CPG], qq[CPG];
    #pragma unroll
    for (int ci = 0; ci < CPG; ++ci) {
        const size_t base = (size_t)(b2 * NC + c0 + ci);
        eq[ci] = __expf(ac * Ssum[base * DDIM + d2]);
        qq[ci] = Q[base * (DDIM * NST) + r];
    }
    float E = 1.f, H = 0.f;
    #pragma unroll
    for (int ci = 0; ci < CPG; ++ci) { H = fmaf(eq[ci], H, qq[ci]); E *= eq[ci]; }

    float oE = __shfl_up(E, 16, 64);
    float oH = __shfl_up(H, 16, 64);
    if (lane >= 16) { H = fmaf(E, oH, H); E *= oE; }
    oE = __shfl_up(E, 32, 64);
    oH = __shfl_up(H, 32, 64);
    if (lane >= 32) { H = fmaf(E, oH, H); E *= oE; }

    float hin = __shfl_up(H, 16, 64);   // exclusive
    if (g == 0) hin = 0.f;

    float h = hin;
    #pragma unroll
    for (int ci = 0; ci < CPG; ++ci) {
        const size_t base = (size_t)(b2 * NC + c0 + ci);
        Hin[base * (DDIM * NST) + r] = h;
        h = fmaf(eq[ci], h, qq[ci]);
    }
}

// ================= pass2: LDS-staged replay with output =================
__global__ __launch_bounds__(256) void pass2_kernel(
    const float* __restrict__ x, const float* __restrict__ A_log,
    const float* __restrict__ Wd, const float* __restrict__ bd,
    const float* __restrict__ Bp, const float* __restrict__ Cc,
    const float* __restrict__ s1, const float* __restrict__ Hin,
    float* __restrict__ out)
{
    __shared__ float xs[CS][256];   // 32 KB
    __shared__ float bs[CS][NST];   // 2 KB
    __shared__ float cs[CS][NST];   // 2 KB
    __shared__ float ss[CS];

    const int tid = threadIdx.x;
    const int d0 = blockIdx.x * 256;
    const int d = d0 + tid;
    const int c = blockIdx.y, b = blockIdx.z;
    const int rowbase = b * LSEQ + c * CS;

    // ---- bulk staging ----
    {
        const float4* xg = (const float4*)(x + (size_t)rowbase * DDIM + d0);
        #pragma unroll
        for (int i = 0; i < (CS * 256 / 4) / 256; ++i) {       // 8 iters
            const int flat = i * 256 + tid;
            const int r = flat >> 6, q = flat & 63;
            const float4 v = xg[(size_t)r * (DDIM / 4) + q];
            float* p = &xs[r][q * 4];
            p[0] = v.x; p[1] = v.y; p[2] = v.z; p[3] = v.w;
        }
        if (tid < CS * NST / 4) {                              // threads 0..127 -> B
            const float4 v = ((const float4*)(Bp + (size_t)rowbase * NST))[tid];
            const int r = tid >> 2, q = tid & 3;
            float* p = &bs[r][q * 4];
            p[0] = v.x; p[1] = v.y; p[2] = v.z; p[3] = v.w;
        } else {                                               // threads 128..255 -> C
            const int t2 = tid - 128;
            const float4 v = ((const float4*)(Cc + (size_t)rowbase * NST))[t2];
            const int r = t2 >> 2, q = t2 & 3;
            float* p = &cs[r][q * 4];
            p[0] = v.x; p[1] = v.y; p[2] = v.z; p[3] = v.w;
        }
        if (tid < CS) ss[tid] = s1[rowbase + tid];
    }

    const float wd = Wd[d], bdv = bd[d];
    float acoef[NST];
    #pragma unroll
    for (int n = 0; n < NST; ++n) acoef[n] = -__expf(A_log[d * NST + n]);
    const float a0 = acoef[0];
    const bool structured = a_structured(acoef);

    float h[NST];
    const size_t gbase = (((size_t)b * NC + c) * DDIM + d) * NST;
    const float4* H4 = (const float4*)(Hin + gbase);
    #pragma unroll
    for (int q = 0; q < 4; ++q) {
        const float4 hv = H4[q];
        h[q * 4] = hv.x; h[q * 4 + 1] = hv.y; h[q * 4 + 2] = hv.z; h[q * 4 + 3] = hv.w;
    }

    __syncthreads();

    float* yp = out + (size_t)rowbase * DDIM + d;

    if (structured) {
        #pragma unroll 4
        for (int l = 0; l < CS; ++l) {
            const float delta = softplus_f(fmaf(ss[l], wd, bdv));
            float e[NST];
            powers16(__expf(delta * a0), e);
            const float dx = delta * xs[l][tid];
            const float4 b0 = *(const float4*)&bs[l][0];
            const float4 b1v = *(const float4*)&bs[l][4];
            const float4 b2 = *(const float4*)&bs[l][8];
            const float4 b3v = *(const float4*)&bs[l][12];
            const float4 c0v = *(const float4*)&cs[l][0];
            const float4 c1v = *(const float4*)&cs[l][4];
            const float4 c2v = *(const float4*)&cs[l][8];
            const float4 c3v = *(const float4*)&cs[l][12];
            const float bv[NST] = {b0.x, b0.y, b0.z, b0.w, b1v.x, b1v.y, b1v.z, b1v.w,
                                   b2.x, b2.y, b2.z, b2.w, b3v.x, b3v.y, b3v.z, b3v.w};
            const float cv[NST] = {c0v.x, c0v.y, c0v.z, c0v.w, c1v.x, c1v.y, c1v.z, c1v.w,
                                   c2v.x, c2v.y, c2v.z, c2v.w, c3v.x, c3v.y, c3v.z, c3v.w};
            float y = 0.f;
            #pragma unroll
            for (int n = 0; n < NST; ++n) {
                h[n] = fmaf(e[n], h[n], dx * bv[n]);
                y = fmaf(h[n], cv[n], y);
            }
            yp[(size_t)l * DDIM] = y;
        }
    } else {
        #pragma unroll 4
        for (int l = 0; l < CS; ++l) {
            const float delta = softplus_f(fmaf(ss[l], wd, bdv));
            float e[NST];
            #pragma unroll
            for (int n = 0; n < NST; ++n) e[n] = __expf(delta * acoef[n]);
            const float dx = delta * xs[l][tid];
            const float4 b0 = *(const float4*)&bs[l][0];
            const float4 b1v = *(const float4*)&bs[l][4];
            const float4 b2 = *(const float4*)&bs[l][8];
            const float4 b3v = *(const float4*)&bs[l][12];
            const float4 c0v = *(const float4*)&cs[l][0];
            const float4 c1v = *(const float4*)&cs[l][4];
            const float4 c2v = *(const float4*)&cs[l][8];
            const float4 c3v = *(const float4*)&cs[l][12];
            const float bv[NST] = {b0.x, b0.y, b0.z, b0.w, b1v.x, b1v.y, b1v.z, b1v.w,
                                   b2.x, b2.y, b2.z, b2.w, b3v.x, b3v.y, b3v.z, b3v.w};
            const float cv[NST] = {c0v.x, c0v.y, c0v.z, c0v.w, c1v.x, c1v.y, c1v.z, c1v.w,
                                   c2v.x, c2v.y, c2v.z, c2v.w, c3v.x, c3v.y, c3v.z, c3v.w};
            float y = 0.f;
            #pragma unroll
            for (int n = 0; n < NST; ++n) {
                h[n] = fmaf(e[n], h[n], dx * bv[n]);
                y = fmaf(h[n], cv[n], y);
            }
            yp[(size_t)l * DDIM] = y;
        }
    }
}

extern "C" void kernel_launch(void* const* d_in, const int* in_sizes, int n_in,
                              void* d_out, int out_size, void* d_ws, size_t ws_size,
                              hipStream_t stream) {
    const float* x     = (const float*)d_in[0];
    const float* A_log = (const float*)d_in[1];
    const float* Wb    = (const float*)d_in[2];
    const float* bb    = (const float*)d_in[3];
    const float* Wc    = (const float*)d_in[4];
    const float* bc    = (const float*)d_in[5];
    const float* W1    = (const float*)d_in[6];
    const float* b1    = (const float*)d_in[7];
    const float* Wd    = (const float*)d_in[8];
    const float* bd    = (const float*)d_in[9];
    float* out = (float*)d_out;

    float* ws = (float*)d_ws;
    const size_t partN = (size_t)KSPL * NJ * NROW;     // 4.33M floats
    const size_t BpN = (size_t)NROW * NST;
    const size_t s1N = (size_t)NROW;
    const size_t sN  = (size_t)B_SZ * NC * DDIM;
    const size_t agg = (size_t)B_SZ * NC * DDIM * NST;

    float* part = ws;
    float* Bp   = part + partN;
    float* Cc   = Bp + BpN;
    float* s1   = Cc + BpN;
    float* Ssum = s1 + s1N;
    float* Q    = Ssum + sN;
    float* Hin  = Q + agg;

    dim3 gproj(NROW / 256, KSPL);
    proj_part_kernel<<<gproj, 256, 0, stream>>>(x, Wb, Wc, W1, part);
    proj_reduce_kernel<<<(NJ * NROW + 255) / 256, 256, 0, stream>>>(part, bb, bc, b1, Bp, Cc, s1);

    dim3 gscan(DDIM / 256, NC, B_SZ);
    pass1_kernel<<<gscan, 256, 0, stream>>>(x, A_log, Wd, bd, Bp, s1, Ssum, Q);
    combine_kernel<<<(B_SZ * DDIM * NST * 4) / 256, 256, 0, stream>>>(A_log, Ssum, Q, Hin);
    pass2_kernel<<<gscan, 256, 0, stream>>>(x, A_log, Wd, bd, Bp, Cc, s1, Hin, out);
}

// Round 8
// 155.023 us; speedup vs baseline: 1.3321x; 1.0391x over previous
//
#include <hip/hip_runtime.h>
#include <math.h>

#define B_SZ 4
#define LSEQ 2048
#define DDIM 768
#define NST  16
#define NROW (B_SZ * LSEQ)      // 8192
#define NJ   33                 // 16 B + 16 C + 1 s1

#define NC   128
#define CS   (LSEQ / NC)        // 16

// ================= projection: thread=(row, k-slice), W via s_load =================
#define KSPL 32
#define KCH  (DDIM / KSPL)      // 24 floats per slice

// grid (NROW/256, KSPL) = (32, 32), block 256. lane = row -> W addr wave-uniform.
__global__ __launch_bounds__(256) void proj_part_kernel(
    const float* __restrict__ x,
    const float* __restrict__ Wb, const float* __restrict__ Wc,
    const float* __restrict__ W1, float* __restrict__ part)
{
    const int row = blockIdx.x * 256 + threadIdx.x;
    const int s = blockIdx.y;
    const int k0 = s * KCH;

    // 24 x-floats in registers (6 float4, 16B-aligned since 24*4B=96B)
    float4 xv[6];
    const float* xp = x + (size_t)row * DDIM + k0;
    #pragma unroll
    for (int q = 0; q < 6; ++q) xv[q] = *(const float4*)(xp + q * 4);

    float acc[NJ];
    #pragma unroll
    for (int j = 0; j < NJ; ++j) {
        const float* wrow = (j < 16) ? (Wb + j * DDIM)
                          : (j < 32) ? (Wc + (j - 16) * DDIM)
                                     : W1;
        const float* wk = wrow + k0;   // lane-invariant -> s_load stream
        float a = 0.f;
        #pragma unroll
        for (int q = 0; q < 6; ++q) {
            a = fmaf(xv[q].x, wk[q * 4 + 0], a);
            a = fmaf(xv[q].y, wk[q * 4 + 1], a);
            a = fmaf(xv[q].z, wk[q * 4 + 2], a);
            a = fmaf(xv[q].w, wk[q * 4 + 3], a);
        }
        acc[j] = a;
    }
    #pragma unroll
    for (int j = 0; j < NJ; ++j)
        part[((size_t)s * NJ + j) * NROW + row] = acc[j];
}

// idx over NJ*NROW; sums KSPL partials, adds bias, scatters to Bp/Cc/s1
__global__ __launch_bounds__(256) void proj_reduce_kernel(
    const float* __restrict__ part,
    const float* __restrict__ bb, const float* __restrict__ bc,
    const float* __restrict__ b1,
    float* __restrict__ Bp, float* __restrict__ Cc, float* __restrict__ s1)
{
    const int idx = blockIdx.x * 256 + threadIdx.x;
    if (idx >= NJ * NROW) return;
    const int j = idx / NROW;
    const int row = idx % NROW;
    float a = 0.f;
    #pragma unroll 8
    for (int s = 0; s < KSPL; ++s)
        a += part[((size_t)s * NJ + j) * NROW + row];
    if (j < 16)      Bp[(size_t)row * NST + j] = a + bb[j];
    else if (j < 32) Cc[(size_t)row * NST + (j - 16)] = a + bc[j - 16];
    else             s1[row] = a + b1[0];
}

// ================= scan =================
__device__ __forceinline__ float softplus_f(float z) {
    float t = __expf(-fabsf(z));
    return fmaxf(z, 0.f) + __logf(1.f + t);
}

// e[n] = p^(n+1), depth-4 multiply tree
__device__ __forceinline__ void powers16(float p, float* e) {
    e[0] = p;      e[1] = p * p;      e[2] = e[1] * p;   e[3] = e[1] * e[1];
    e[4] = e[3] * p;  e[5] = e[3] * e[1];  e[6] = e[3] * e[2];  e[7] = e[3] * e[3];
    e[8] = e[7] * p;  e[9] = e[7] * e[1];  e[10] = e[7] * e[2]; e[11] = e[7] * e[3];
    e[12] = e[7] * e[4]; e[13] = e[7] * e[5]; e[14] = e[7] * e[6]; e[15] = e[7] * e[7];
}

__device__ __forceinline__ bool a_structured(const float* acoef) {
    bool st = true;
    #pragma unroll
    for (int n = 0; n < NST; ++n)
        st = st && (fabsf(acoef[n] - (float)(n + 1) * acoef[0]) <= 1e-5f * fabsf(acoef[n]));
    return __all(st) != 0;
}

__global__ __launch_bounds__(256) void pass1_kernel(
    const float* __restrict__ x, const float* __restrict__ A_log,
    const float* __restrict__ Wd, const float* __restrict__ bd,
    const float* __restrict__ Bp, const float* __restrict__ s1,
    float* __restrict__ Ssum, float* __restrict__ Q)
{
    const int tid = threadIdx.x;
    const int d = blockIdx.x * 256 + tid;
    const int c = blockIdx.y, b = blockIdx.z;
    const int rowbase = b * LSEQ + c * CS;

    const float wd = Wd[d], bdv = bd[d];
    float acoef[NST];
    #pragma unroll
    for (int n = 0; n < NST; ++n) acoef[n] = -__expf(A_log[d * NST + n]);
    const float a0 = acoef[0];
    const bool structured = a_structured(acoef);

    const float4* B4 = (const float4*)(Bp + (size_t)rowbase * NST);
    const float* s1p = s1 + rowbase;
    const float* xp = x + (size_t)rowbase * DDIM + d;

    float h[NST];
    #pragma unroll
    for (int n = 0; n < NST; ++n) h[n] = 0.f;
    float S = 0.f;

    if (structured) {
        #pragma unroll 4
        for (int l = 0; l < CS; ++l) {
            const float delta = softplus_f(fmaf(s1p[l], wd, bdv));
            S += delta;
            float e[NST];
            powers16(__expf(delta * a0), e);
            const float dx = delta * xp[(size_t)l * DDIM];
            const float4 b0 = B4[l * 4 + 0], b1v = B4[l * 4 + 1];
            const float4 b2 = B4[l * 4 + 2], b3v = B4[l * 4 + 3];
            const float bv[NST] = {b0.x, b0.y, b0.z, b0.w, b1v.x, b1v.y, b1v.z, b1v.w,
                                   b2.x, b2.y, b2.z, b2.w, b3v.x, b3v.y, b3v.z, b3v.w};
            #pragma unroll
            for (int n = 0; n < NST; ++n) h[n] = fmaf(e[n], h[n], dx * bv[n]);
        }
    } else {
        #pragma unroll 4
        for (int l = 0; l < CS; ++l) {
            const float delta = softplus_f(fmaf(s1p[l], wd, bdv));
            S += delta;
            float e[NST];
            #pragma unroll
            for (int n = 0; n < NST; ++n) e[n] = __expf(delta * acoef[n]);
            const float dx = delta * xp[(size_t)l * DDIM];
            const float4 b0 = B4[l * 4 + 0], b1v = B4[l * 4 + 1];
            const float4 b2 = B4[l * 4 + 2], b3v = B4[l * 4 + 3];
            const float bv[NST] = {b0.x, b0.y, b0.z, b0.w, b1v.x, b1v.y, b1v.z, b1v.w,
                                   b2.x, b2.y, b2.z, b2.w, b3v.x, b3v.y, b3v.z, b3v.w};
            #pragma unroll
            for (int n = 0; n < NST; ++n) h[n] = fmaf(e[n], h[n], dx * bv[n]);
        }
    }
    Ssum[((size_t)b * NC + c) * DDIM + d] = S;
    const size_t gbase = (((size_t)b * NC + c) * DDIM + d) * NST;
    float4* Q4 = (float4*)(Q + gbase);
    #pragma unroll
    for (int q = 0; q < 4; ++q)
        Q4[q] = make_float4(h[q * 4], h[q * 4 + 1], h[q * 4 + 2], h[q * 4 + 3]);
}

// ---------- combine: 4-way split of the chunk scan + shfl compose ----------
// (E2,H2) after (E1,H1):  E = E1*E2,  H = E2*H1 + H2   (associative)
#define CPG (NC / 4)   // 32 chunks per group
__global__ __launch_bounds__(256) void combine_kernel(
    const float* __restrict__ A_log,
    const float* __restrict__ Ssum, const float* __restrict__ Q,
    float* __restrict__ Hin)
{
    const int gidx = blockIdx.x * 256 + threadIdx.x;  // over B*D*N*4 = 196608
    const int lane = threadIdx.x & 63;
    const int rlow = gidx & 15;
    const int g = (gidx >> 4) & 3;
    const int hi = gidx >> 6;
    const int pairIdx = hi * 16 + rlow;               // [0, B*D*N)
    const int b = pairIdx / (DDIM * NST);
    const int r = pairIdx % (DDIM * NST);
    const int d = r >> 4;
    const float acoef = -__expf(A_log[r]);
    const int c0 = g * CPG;

    float eq[CPG], qq[CPG];
    #pragma unroll
    for (int ci = 0; ci < CPG; ++ci) {
        const size_t base = (size_t)(b * NC + c0 + ci);
        eq[ci] = __expf(acoef * Ssum[base * DDIM + d]);
        qq[ci] = Q[base * (DDIM * NST) + r];
    }
    float E = 1.f, H = 0.f;
    #pragma unroll
    for (int ci = 0; ci < CPG; ++ci) { H = fmaf(eq[ci], H, qq[ci]); E *= eq[ci]; }

    // inclusive Kogge-Stone over the 4 groups (lanes 16 apart)
    float oE = __shfl_up(E, 16, 64);
    float oH = __shfl_up(H, 16, 64);
    if (lane >= 16) { H = fmaf(E, oH, H); E *= oE; }
    oE = __shfl_up(E, 32, 64);
    oH = __shfl_up(H, 32, 64);
    if (lane >= 32) { H = fmaf(E, oH, H); E *= oE; }

    float hin = __shfl_up(H, 16, 64);   // exclusive
    if (g == 0) hin = 0.f;

    float h = hin;
    #pragma unroll
    for (int ci = 0; ci < CPG; ++ci) {
        const size_t base = (size_t)(b * NC + c0 + ci);
        Hin[base * (DDIM * NST) + r] = h;
        h = fmaf(eq[ci], h, qq[ci]);
    }
}

__global__ __launch_bounds__(256) void pass2_kernel(
    const float* __restrict__ x, const float* __restrict__ A_log,
    const float* __restrict__ Wd, const float* __restrict__ bd,
    const float* __restrict__ Bp, const float* __restrict__ Cc,
    const float* __restrict__ s1, const float* __restrict__ Hin,
    float* __restrict__ out)
{
    const int tid = threadIdx.x;
    const int d = blockIdx.x * 256 + tid;
    const int c = blockIdx.y, b = blockIdx.z;
    const int rowbase = b * LSEQ + c * CS;

    const float wd = Wd[d], bdv = bd[d];
    float acoef[NST];
    #pragma unroll
    for (int n = 0; n < NST; ++n) acoef[n] = -__expf(A_log[d * NST + n]);
    const float a0 = acoef[0];
    const bool structured = a_structured(acoef);

    const float4* B4 = (const float4*)(Bp + (size_t)rowbase * NST);
    const float4* C4 = (const float4*)(Cc + (size_t)rowbase * NST);
    const float* s1p = s1 + rowbase;
    const float* xp = x + (size_t)rowbase * DDIM + d;
    float* yp = out + (size_t)rowbase * DDIM + d;

    float h[NST];
    const size_t gbase = (((size_t)b * NC + c) * DDIM + d) * NST;
    const float4* H4 = (const float4*)(Hin + gbase);
    #pragma unroll
    for (int q = 0; q < 4; ++q) {
        const float4 hv = H4[q];
        h[q * 4] = hv.x; h[q * 4 + 1] = hv.y; h[q * 4 + 2] = hv.z; h[q * 4 + 3] = hv.w;
    }

    if (structured) {
        #pragma unroll 4
        for (int l = 0; l < CS; ++l) {
            const float delta = softplus_f(fmaf(s1p[l], wd, bdv));
            float e[NST];
            powers16(__expf(delta * a0), e);
            const float dx = delta * xp[(size_t)l * DDIM];
            const float4 b0 = B4[l * 4 + 0], b1v = B4[l * 4 + 1];
            const float4 b2 = B4[l * 4 + 2], b3v = B4[l * 4 + 3];
            const float4 c0 = C4[l * 4 + 0], c1v = C4[l * 4 + 1];
            const float4 c2 = C4[l * 4 + 2], c3v = C4[l * 4 + 3];
            const float bv[NST] = {b0.x, b0.y, b0.z, b0.w, b1v.x, b1v.y, b1v.z, b1v.w,
                                   b2.x, b2.y, b2.z, b2.w, b3v.x, b3v.y, b3v.z, b3v.w};
            const float cv[NST] = {c0.x, c0.y, c0.z, c0.w, c1v.x, c1v.y, c1v.z, c1v.w,
                                   c2.x, c2.y, c2.z, c2.w, c3v.x, c3v.y, c3v.z, c3v.w};
            float y = 0.f;
            #pragma unroll
            for (int n = 0; n < NST; ++n) {
                h[n] = fmaf(e[n], h[n], dx * bv[n]);
                y = fmaf(h[n], cv[n], y);
            }
            yp[(size_t)l * DDIM] = y;
        }
    } else {
        #pragma unroll 4
        for (int l = 0; l < CS; ++l) {
            const float delta = softplus_f(fmaf(s1p[l], wd, bdv));
            float e[NST];
            #pragma unroll
            for (int n = 0; n < NST; ++n) e[n] = __expf(delta * acoef[n]);
            const float dx = delta * xp[(size_t)l * DDIM];
            const float4 b0 = B4[l * 4 + 0], b1v = B4[l * 4 + 1];
            const float4 b2 = B4[l * 4 + 2], b3v = B4[l * 4 + 3];
            const float4 c0 = C4[l * 4 + 0], c1v = C4[l * 4 + 1];
            const float4 c2 = C4[l * 4 + 2], c3v = C4[l * 4 + 3];
            const float bv[NST] = {b0.x, b0.y, b0.z, b0.w, b1v.x, b1v.y, b1v.z, b1v.w,
                                   b2.x, b2.y, b2.z, b2.w, b3v.x, b3v.y, b3v.z, b3v.w};
            const float cv[NST] = {c0.x, c0.y, c0.z, c0.w, c1v.x, c1v.y, c1v.z, c1v.w,
                                   c2.x, c2.y, c2.z, c2.w, c3v.x, c3v.y, c3v.z, c3v.w};
            float y = 0.f;
            #pragma unroll
            for (int n = 0; n < NST; ++n) {
                h[n] = fmaf(e[n], h[n], dx * bv[n]);
                y = fmaf(h[n], cv[n], y);
            }
            yp[(size_t)l * DDIM] = y;
        }
    }
}

extern "C" void kernel_launch(void* const* d_in, const int* in_sizes, int n_in,
                              void* d_out, int out_size, void* d_ws, size_t ws_size,
                              hipStream_t stream) {
    const float* x     = (const float*)d_in[0];
    const float* A_log = (const float*)d_in[1];
    const float* Wb    = (const float*)d_in[2];
    const float* bb    = (const float*)d_in[3];
    const float* Wc    = (const float*)d_in[4];
    const float* bc    = (const float*)d_in[5];
    const float* W1    = (const float*)d_in[6];
    const float* b1    = (const float*)d_in[7];
    const float* Wd    = (const float*)d_in[8];
    const float* bd    = (const float*)d_in[9];
    float* out = (float*)d_out;

    float* ws = (float*)d_ws;
    const size_t partN = (size_t)KSPL * NJ * NROW;     // 8.65M floats = 34.6MB
    const size_t BpN = (size_t)NROW * NST;             // 131072
    const size_t s1N = (size_t)NROW;                   // 8192
    const size_t sN  = (size_t)B_SZ * NC * DDIM;       // 393216
    const size_t agg = (size_t)B_SZ * NC * DDIM * NST; // 6.29M

    float* part = ws;
    float* Bp   = part + partN;
    float* Cc   = Bp + BpN;
    float* s1   = Cc + BpN;
    float* Ssum = s1 + s1N;
    float* Q    = Ssum + sN;
    float* Hin  = Q + agg;

    dim3 gproj(NROW / 256, KSPL);
    proj_part_kernel<<<gproj, 256, 0, stream>>>(x, Wb, Wc, W1, part);
    proj_reduce_kernel<<<(NJ * NROW + 255) / 256, 256, 0, stream>>>(part, bb, bc, b1, Bp, Cc, s1);

    dim3 gscan(DDIM / 256, NC, B_SZ);
    pass1_kernel<<<gscan, 256, 0, stream>>>(x, A_log, Wd, bd, Bp, s1, Ssum, Q);

    combine_kernel<<<(B_SZ * DDIM * NST * 4) / 256, 256, 0, stream>>>(A_log, Ssum, Q, Hin);

    pass2_kernel<<<gscan, 256, 0, stream>>>(x, A_log, Wd, bd, Bp, Cc, s1, Hin, out);
}